// Round 5
// baseline (1669.190 us; speedup 1.0000x reference)
//
#include <hip/hip_runtime.h>
#include <stdint.h>

// Fused 2-layer LSTM: B=2048, T=512, F=32, H=128, G=512. Grid 256 WGs x 256
// threads (4 waves) = 1 WG/CU, 1 wave/SIMD -> 512-reg budget (256 VGPR + 256
// AGPR) per wave. Each WG owns 8 batch rows; wave w owns hidden-col groups
// {w, w+4} (16 cols each) for all 4 gates of both layers.
// Skewed single loop: iter tau = L1 step tau-1 (first) then L0 step tau, so
// L0's MFMAs issue under L1's gate VALU (single-wave pipe overlap).
// M=16 MFMA tile, 8 real rows with SWIZZLED duplication: A row m holds real
// row f(m)=((m&12)>>1)|(m&1), so D rows 4q+{0,1} = real rows {2q,2q+1} ->
// gate extraction uses STATIC acc indices {0,1} (no dynamic vector extract).
// Weights: Whh0/Wih1/Whh1 B-frags in registers (384 regs, VGPR+AGPR);
// Wih0 streamed from a conflict-free 32 KB LDS image. h0/h1 pass through
// LDS double-buffers; h-writes pair-packed to b32 via shfl+cvt_pkrtz.

#define B_ 2048
#define T_ 512
#define F_ 32
#define H_ 128
#define LSTR 136                 // halves per h row: 17*16B -> A-reads conflict-free
#define H0SZ (8 * LSTR)
#define LOG2E 1.4426950408889634f

typedef _Float16 half8 __attribute__((ext_vector_type(8)));
typedef _Float16 half2_t __attribute__((ext_vector_type(2)));
typedef float float4_t __attribute__((ext_vector_type(4)));

// lgkm-only barrier: don't drain vmcnt (global x prefetch stays in flight)
#define BARRIER_LGKM() asm volatile("s_waitcnt lgkmcnt(0)\n\ts_barrier" ::: "memory")

__device__ __forceinline__ float fexp2(float x) {
  float r; asm("v_exp_f32 %0, %1" : "=v"(r) : "v"(x)); return r;
}
__device__ __forceinline__ float frcp(float x) { return __builtin_amdgcn_rcpf(x); }

__device__ __forceinline__ half2_t pack2(float a, float b) {
  return __builtin_bit_cast(half2_t, __builtin_amdgcn_cvt_pkrtz(a, b));
}

__device__ __forceinline__ half8 cvt2f4(float4_t a, float4_t b) {
  half8 r;
  r[0] = (_Float16)a[0]; r[1] = (_Float16)a[1]; r[2] = (_Float16)a[2]; r[3] = (_Float16)a[3];
  r[4] = (_Float16)b[0]; r[5] = (_Float16)b[1]; r[6] = (_Float16)b[2]; r[7] = (_Float16)b[3];
  return r;
}
__device__ __forceinline__ half8 load8cvt(const float* p) {
  return cvt2f4(*(const float4_t*)p, *(const float4_t*)(p + 4));
}

__global__ __launch_bounds__(256, 1) void lstm_fused(
    const float* __restrict__ x, const float* __restrict__ Wih0,
    const float* __restrict__ Whh0, const float* __restrict__ b0,
    const float* __restrict__ Wih1, const float* __restrict__ Whh1,
    const float* __restrict__ b1, const float* __restrict__ Wfc,
    const float* __restrict__ bfc, float* __restrict__ out)
{
  // Wih0 image: slot(c16,j,n,q) -> consecutive lanes (n,q) hit distinct 16B
  // bank groups -> conflict-free b128 with no padding. 16384 halves = 32 KB.
  __shared__ __attribute__((aligned(16))) _Float16 lds_w0[8 * 4 * 16 * 4 * 8];
  __shared__ __attribute__((aligned(16))) _Float16 lds_h0[2 * H0SZ];
  __shared__ __attribute__((aligned(16))) _Float16 lds_h1[2 * H0SZ];
  __shared__ float lds_fc[4][8];

  const int tid  = threadIdx.x;
  const int w    = tid >> 6;               // wave 0..3
  const int lane = tid & 63;
  const int n    = lane & 15;
  const int q    = lane >> 4;
  const int rbase = (int)blockIdx.x * 8;
  const int fr   = ((n & 12) >> 1) | (n & 1);   // swizzled dup: A row -> real row
  const int aoff = fr * LSTR + q * 8;           // A-frag LDS offset (halves)

  // ---- setup: big weights -> regs, Wih0 -> LDS, folded biases ----
  half8 bwhh0[2][4][4], bwih1[2][4][4], bwhh1[2][4][4];
  float cI[2][2], cF[2][2], cG[2][2], cO[2][2];   // [layer][cg]
  float wfcv[2];
#pragma unroll
  for (int cg = 0; cg < 2; ++cg) {
    const int c16 = w + 4 * cg;
    const int col = c16 * 16 + n;
#pragma unroll
    for (int j = 0; j < 4; ++j) {
      const int g = j * H_ + col;
#pragma unroll
      for (int kc = 0; kc < 4; ++kc) {
        bwhh0[cg][j][kc] = load8cvt(Whh0 + g * H_ + kc * 32 + q * 8);
        bwih1[cg][j][kc] = load8cvt(Wih1 + g * H_ + kc * 32 + q * 8);
        bwhh1[cg][j][kc] = load8cvt(Whh1 + g * H_ + kc * 32 + q * 8);
      }
      *(half8*)(lds_w0 + (((c16 * 4 + j) * 16 + n) * 4 + q) * 8) =
          load8cvt(Wih0 + g * F_ + q * 8);
    }
    cI[0][cg] = -b0[0 * H_ + col] * LOG2E;
    cF[0][cg] = -b0[1 * H_ + col] * LOG2E;
    cG[0][cg] =  b0[2 * H_ + col] * (2.0f * LOG2E);
    cO[0][cg] = -b0[3 * H_ + col] * LOG2E;
    cI[1][cg] = -b1[0 * H_ + col] * LOG2E;
    cF[1][cg] = -b1[1 * H_ + col] * LOG2E;
    cG[1][cg] =  b1[2 * H_ + col] * (2.0f * LOG2E);
    cO[1][cg] = -b1[3 * H_ + col] * LOG2E;
    wfcv[cg] = Wfc[col];
  }
  for (int i = tid; i < 2 * H0SZ; i += 256) {
    lds_h0[i] = (_Float16)0.0f; lds_h1[i] = (_Float16)0.0f;
  }
  __syncthreads();

  const float4_t zC = {0.f, 0.f, 0.f, 0.f};
  float c0s[2][2] = {{0.f, 0.f}, {0.f, 0.f}};   // [cg][rr] layer 0 cell
  float c1s[2][2] = {{0.f, 0.f}, {0.f, 0.f}};   // layer 1 cell
  float hl[2][2]  = {{0.f, 0.f}, {0.f, 0.f}};   // last layer-1 h

  const float* xp = x + (rbase + fr) * (T_ * F_) + q * 8;
  float4_t xrA = *(const float4_t*)(xp);
  float4_t xrB = *(const float4_t*)(xp + 4);
  const int w0off0 = (((w + 0) * 4) * 16 + n) * 32 + q * 8;
  const int w0off1 = (((w + 4) * 4) * 16 + n) * 32 + q * 8;

#pragma unroll 1
  for (int tau = 0; tau <= T_; ++tau) {
    const int pw = tau & 1;
    const _Float16* h0rd = lds_h0 + (pw ^ 1) * H0SZ;  // h0(tau-1)
    _Float16*       h0wr = lds_h0 + pw * H0SZ;        // h0(tau)
    const _Float16* h1rd = lds_h1 + pw * H0SZ;        // h1(tau-2)
    _Float16*       h1wr = lds_h1 + (pw ^ 1) * H0SZ;  // h1(tau-1)
    const bool do0 = (tau < T_), do1 = (tau >= 1);

    half8 ah[4];                                      // h0(tau-1), shared A
#pragma unroll
    for (int kc = 0; kc < 4; ++kc)
      ah[kc] = *(const half8*)(h0rd + aoff + kc * 32);

    float4_t acc[2][4];
    float z1[2][4][2];
    if (do1) {                                        // ---- L1 step tau-1 MFMA
      half8 a1h[4];
#pragma unroll
      for (int kc = 0; kc < 4; ++kc)
        a1h[kc] = *(const half8*)(h1rd + aoff + kc * 32);
#pragma unroll
      for (int kc = 0; kc < 4; ++kc)
#pragma unroll
        for (int cg = 0; cg < 2; ++cg)
#pragma unroll
          for (int j = 0; j < 4; ++j)
            acc[cg][j] = __builtin_amdgcn_mfma_f32_16x16x32_f16(
                ah[kc], bwih1[cg][j][kc], kc == 0 ? zC : acc[cg][j], 0, 0, 0);
#pragma unroll
      for (int kc = 0; kc < 4; ++kc)
#pragma unroll
        for (int cg = 0; cg < 2; ++cg)
#pragma unroll
          for (int j = 0; j < 4; ++j)
            acc[cg][j] = __builtin_amdgcn_mfma_f32_16x16x32_f16(
                a1h[kc], bwhh1[cg][j][kc], acc[cg][j], 0, 0, 0);
#pragma unroll
      for (int cg = 0; cg < 2; ++cg)                  // static extract {0,1}
#pragma unroll
        for (int j = 0; j < 4; ++j) {
          z1[cg][j][0] = acc[cg][j][0];
          z1[cg][j][1] = acc[cg][j][1];
        }
    }

    if (do0) {                                        // ---- L0 step tau MFMA
      half8 ax = cvt2f4(xrA, xrB);
#pragma unroll
      for (int cg = 0; cg < 2; ++cg) {
        const int wo = cg ? w0off1 : w0off0;
#pragma unroll
        for (int j = 0; j < 4; ++j) {
          half8 f0 = *(const half8*)(lds_w0 + wo + j * 512);
          acc[cg][j] = __builtin_amdgcn_mfma_f32_16x16x32_f16(ax, f0, zC, 0, 0, 0);
        }
      }
#pragma unroll
      for (int kc = 0; kc < 4; ++kc)
#pragma unroll
        for (int cg = 0; cg < 2; ++cg)
#pragma unroll
          for (int j = 0; j < 4; ++j)
            acc[cg][j] = __builtin_amdgcn_mfma_f32_16x16x32_f16(
                ah[kc], bwhh0[cg][j][kc], acc[cg][j], 0, 0, 0);
      const int tn = (tau + 1 < T_) ? tau + 1 : T_ - 1;     // x prefetch
      xrA = *(const float4_t*)(xp + tn * F_);
      xrB = *(const float4_t*)(xp + tn * F_ + 4);
    }

    if (do1) {                                        // ---- L1 gates (VALU,
#pragma unroll                                        //      overlaps L0 MFMA pipe)
      for (int cg = 0; cg < 2; ++cg)
#pragma unroll
        for (int rr = 0; rr < 2; ++rr) {
          const float gi = frcp(1.0f + fexp2(__builtin_fmaf(z1[cg][0][rr], -LOG2E, cI[1][cg])));
          const float gf = frcp(1.0f + fexp2(__builtin_fmaf(z1[cg][1][rr], -LOG2E, cF[1][cg])));
          const float gg = 1.0f - 2.0f * frcp(1.0f + fexp2(__builtin_fmaf(z1[cg][2][rr], 2.0f * LOG2E, cG[1][cg])));
          const float go = frcp(1.0f + fexp2(__builtin_fmaf(z1[cg][3][rr], -LOG2E, cO[1][cg])));
          float& cc = c1s[cg][rr];
          cc = __builtin_fmaf(gf, cc, gi * gg);
          const float th = 1.0f - 2.0f * frcp(1.0f + fexp2(cc * (2.0f * LOG2E)));
          const float hv = go * th;
          hl[cg][rr] = hv;
          const float nb = __shfl_xor(hv, 1);
          if (!(n & 1)) {
            *(half2_t*)(h1wr + (2 * q + rr) * LSTR + (w + 4 * cg) * 16 + n) =
                pack2(hv, nb);
          }
        }
    }

    if (do0) {                                        // ---- L0 gates
#pragma unroll
      for (int cg = 0; cg < 2; ++cg)
#pragma unroll
        for (int rr = 0; rr < 2; ++rr) {
          const float gi = frcp(1.0f + fexp2(__builtin_fmaf(acc[cg][0][rr], -LOG2E, cI[0][cg])));
          const float gf = frcp(1.0f + fexp2(__builtin_fmaf(acc[cg][1][rr], -LOG2E, cF[0][cg])));
          const float gg = 1.0f - 2.0f * frcp(1.0f + fexp2(__builtin_fmaf(acc[cg][2][rr], 2.0f * LOG2E, cG[0][cg])));
          const float go = frcp(1.0f + fexp2(__builtin_fmaf(acc[cg][3][rr], -LOG2E, cO[0][cg])));
          float& cc = c0s[cg][rr];
          cc = __builtin_fmaf(gf, cc, gi * gg);
          const float th = 1.0f - 2.0f * frcp(1.0f + fexp2(cc * (2.0f * LOG2E)));
          const float hv = go * th;
          const float nb = __shfl_xor(hv, 1);
          if (!(n & 1)) {
            *(half2_t*)(h0wr + (2 * q + rr) * LSTR + (w + 4 * cg) * 16 + n) =
                pack2(hv, nb);
          }
        }
    }
    BARRIER_LGKM();
  }

  // ---- FC head: out[row] = sum_col h1_last[row][col]*Wfc[col] + bfc ----
  float p0 = __builtin_fmaf(hl[0][0], wfcv[0], hl[1][0] * wfcv[1]);  // row 2q
  float p1 = __builtin_fmaf(hl[0][1], wfcv[0], hl[1][1] * wfcv[1]);  // row 2q+1
#pragma unroll
  for (int m = 1; m < 16; m <<= 1) {
    p0 += __shfl_xor(p0, m);
    p1 += __shfl_xor(p1, m);
  }
  if (n == 0) {
    lds_fc[w][2 * q + 0] = p0;
    lds_fc[w][2 * q + 1] = p1;
  }
  __syncthreads();
  if (tid < 8) {
    float s = bfc[0];
#pragma unroll
    for (int wv = 0; wv < 4; ++wv) s += lds_fc[wv][tid];
    out[rbase + tid] = s;
  }
}

extern "C" void kernel_launch(void* const* d_in, const int* in_sizes, int n_in,
                              void* d_out, int out_size, void* d_ws, size_t ws_size,
                              hipStream_t stream) {
  const float* x    = (const float*)d_in[0];
  const float* Wih0 = (const float*)d_in[1];
  const float* Whh0 = (const float*)d_in[2];
  const float* b0   = (const float*)d_in[3];
  const float* Wih1 = (const float*)d_in[4];
  const float* Whh1 = (const float*)d_in[5];
  const float* b1   = (const float*)d_in[6];
  const float* Wfc  = (const float*)d_in[7];
  const float* bfc  = (const float*)d_in[8];
  float* outp = (float*)d_out;
  (void)d_ws; (void)ws_size;

  lstm_fused<<<B_ / 8, 256, 0, stream>>>(x, Wih0, Whh0, b0, Wih1, Whh1, b1,
                                         Wfc, bfc, outp);
}